// Round 4
// baseline (54.418 us; speedup 1.0000x reference)
//
#include <hip/hip_runtime.h>
#include <math.h>

#define Bb 8
#define Nn 4096
#define Mm 4096
#define QP 8                    // query points per thread (registers)
#define WAVES 8                 // waves per block
#define BLOCK (WAVES * 64)      // 512 threads
#define MQ (Mm / 4)             // 1024 targets per M-quarter (16 KB LDS)
#define SLICE (MQ / WAVES)      // 128 targets per wave
#define QTILES (Nn / (64 * QP)) // 8 query tiles per (dir,b)

// d_ws layout: mins[65536][4] — per-query per-quarter partial (pp + min_quarter)
//   query slot qg = (dir*Bb + b)*Nn + n ; all slots rewritten every call.

// grid = 2 dirs x 8 batches x 8 qtiles x 4 quarters = 512 blocks of 512 thr
// (2 blocks/CU = 16 waves/CU = 4 waves/SIMD; VGPR ~90 <= 128).
// Inner loop: 1 broadcast ds_read_b128 per target per wave, amortized over
// 64 lanes x QP=8 queries -> LDS pipe demand ~10 µs < VALU demand ~12 µs.
__global__ void __launch_bounds__(BLOCK, 4) chamfer_kernel(
    const float* __restrict__ pred,
    const float* __restrict__ targ,
    float* __restrict__ mins)
{
    __shared__ float4 ts[MQ + 8];      // +8 pad for the prefetch pipeline

    const int tid  = threadIdx.x;
    const int lane = tid & 63;
    const int wave = tid >> 6;

    const int id      = blockIdx.x;
    const int quarter = id & 3;
    const int tile    = (id >> 2) & (QTILES - 1);
    const int b       = (id >> 5) & (Bb - 1);
    const int dir     = id >> 8;

    const float* Q = dir ? targ : pred;
    const float* T = dir ? pred : targ;

    // ---- stage this M-quarter as float4(x,y,z,|t|^2) ----
    for (int i = tid; i < MQ; i += BLOCK) {
        const float* g = T + ((size_t)b * Mm + quarter * MQ + i) * 3;
        float x = g[0], y = g[1], z = g[2];
        ts[i] = make_float4(x, y, z, fmaf(x, x, fmaf(y, y, z * z)));
    }
    if (tid < 8) ts[MQ + tid] = make_float4(0.f, 0.f, 0.f, __builtin_inff());

    // ---- this thread's QP query points ----
    float npx[QP], npy[QP], npz[QP], pp[QP], mn[QP];
    #pragma unroll
    for (int q = 0; q < QP; ++q) {
        const int n = tile * (64 * QP) + q * 64 + lane;
        const float* g = Q + ((size_t)b * Nn + n) * 3;
        float x = g[0], y = g[1], z = g[2];
        npx[q] = -2.0f * x;  npy[q] = -2.0f * y;  npz[q] = -2.0f * z;
        pp[q]  = fmaf(x, x, fmaf(y, y, z * z));
        mn[q]  = __builtin_inff();
    }

    __syncthreads();

    // ---- main loop: 4-deep register prefetch over this wave's slice ----
    const float4* tw = ts + wave * SLICE;
    float4 t0 = tw[0], t1 = tw[1], t2 = tw[2], t3 = tw[3];
    for (int m = 0; m < SLICE; m += 4) {
        float4 u0 = tw[m + 4], u1 = tw[m + 5], u2 = tw[m + 6], u3 = tw[m + 7];
        #pragma unroll
        for (int q = 0; q < QP; ++q) {
            float dA = fmaf(npx[q], t0.x, fmaf(npy[q], t0.y, fmaf(npz[q], t0.z, t0.w)));
            float dB = fmaf(npx[q], t1.x, fmaf(npy[q], t1.y, fmaf(npz[q], t1.z, t1.w)));
            mn[q] = fminf(fminf(mn[q], dA), dB);          // -> v_min3_f32
            float dC = fmaf(npx[q], t2.x, fmaf(npy[q], t2.y, fmaf(npz[q], t2.z, t2.w)));
            float dD = fmaf(npx[q], t3.x, fmaf(npy[q], t3.y, fmaf(npz[q], t3.z, t3.w)));
            mn[q] = fminf(fminf(mn[q], dC), dD);          // -> v_min3_f32
        }
        t0 = u0; t1 = u1; t2 = u2; t3 = u3;
    }

    __syncthreads();                    // done reading ts -> reuse as smin
    float* smin = (float*)ts;           // [QP][WAVES][64] = 16 KB
    #pragma unroll
    for (int q = 0; q < QP; ++q)
        smin[(q * WAVES + wave) * 64 + lane] = mn[q];
    __syncthreads();

    // ---- cross-wave min for q == wave (QP == WAVES), write partial ----
    {
        const int q = wave;             // this thread holds pp[q] for its lane
        float v = __builtin_inff();
        #pragma unroll
        for (int w = 0; w < WAVES; ++w)
            v = fminf(v, smin[(q * WAVES + w) * 64 + lane]);
        const int n = tile * (64 * QP) + q * 64 + lane;
        const size_t qg = ((size_t)dir * Bb + b) * Nn + n;
        mins[qg * 4 + quarter] = pp[q] + v;
    }
}

// single block: quarter-min + chamfer/emd/unc sums + final combine
__global__ void __launch_bounds__(1024) reduce_finalize_kernel(
    const float* __restrict__ mins, const float* __restrict__ unc,
    float* __restrict__ out)
{
    const int tid = threadIdx.x;
    const float4* m4 = (const float4*)mins;
    float sA = 0.f, sE = 0.f, sB = 0.f, sU = 0.f;

    for (int i = tid; i < 2 * Bb * Nn; i += 1024) {       // 65536 query slots
        const float4 v = m4[i];
        const float m = fminf(fminf(v.x, v.y), fminf(v.z, v.w));
        if (i < Bb * Nn) { sA += m; sE += sqrtf(fmaxf(m, 0.f)); }
        else             { sB += m; }
    }
    const float4* u4 = (const float4*)unc;
    for (int i = tid; i < (Bb * Nn) / 4; i += 1024) {     // 8192 float4
        const float4 u = u4[i];
        sU += (u.x + u.y) + (u.z + u.w);
    }

    #pragma unroll
    for (int off = 32; off > 0; off >>= 1) {
        sA += __shfl_down(sA, off);  sE += __shfl_down(sE, off);
        sB += __shfl_down(sB, off);  sU += __shfl_down(sU, off);
    }
    __shared__ float sw[16][4];
    const int lane = tid & 63, wave = tid >> 6;
    if (lane == 0) { sw[wave][0] = sA; sw[wave][1] = sE;
                     sw[wave][2] = sB; sw[wave][3] = sU; }
    __syncthreads();
    if (tid == 0) {
        float a = 0.f, e = 0.f, bsum = 0.f, usum = 0.f;
        #pragma unroll
        for (int w = 0; w < 16; ++w) {
            a += sw[w][0]; e += sw[w][1]; bsum += sw[w][2]; usum += sw[w][3];
        }
        const float invBN = 1.0f / (float)(Bb * Nn);
        const float invBM = 1.0f / (float)(Bb * Mm);
        out[0] = (a * invBN + bsum * invBM) + 0.5f * (e * invBN)
               + 0.01f * (usum * invBN);
    }
}

extern "C" void kernel_launch(void* const* d_in, const int* in_sizes, int n_in,
                              void* d_out, int out_size, void* d_ws, size_t ws_size,
                              hipStream_t stream) {
    const float* pred = (const float*)d_in[0];   // [8,4096,3]
    const float* targ = (const float*)d_in[1];   // [8,4096,3]
    const float* unc  = (const float*)d_in[2];   // [8,4096]
    float* out  = (float*)d_out;
    float* mins = (float*)d_ws;                  // 65536 x 4 floats = 1 MB

    chamfer_kernel<<<512, BLOCK, 0, stream>>>(pred, targ, mins);
    reduce_finalize_kernel<<<1, 1024, 0, stream>>>(mins, unc, out);
}

// Round 5
// 33.831 us; speedup vs baseline: 1.6086x; 1.6086x over previous
//
#include <hip/hip_runtime.h>
#include <math.h>

#define Bb 8
#define Nn 4096
#define Mm 4096
#define QP 16                   // query points per thread (registers)
#define WAVES 8                 // waves per block
#define BLOCK (WAVES * 64)      // 512 threads
#define NE 8                    // M split into eighths
#define ME (Mm / NE)            // 512 targets per eighth (8 KB LDS)
#define SLICE (ME / WAVES)      // 64 targets per wave
#define QTILES (Nn / (64 * QP)) // 4 query tiles per (dir,b)
#define NQ (2 * Bb * Nn)        // 65536 query slots (both dirs)

// d_ws layout:
//   mins[NQ][NE]            : per-query per-eighth partial (pp + min_eighth), 2 MB
//   partials[128][4]        : per-reduce-block {chamferA, emd, chamferB, unc} sums
// Every slot is rewritten every call (no memset, no atomics, deterministic).

// grid = 2 dirs x 8 batches x 4 qtiles x 8 eighths = 512 blocks of 512 thr
// (2 blocks/CU, 4 waves/SIMD). Inner loop: 1 broadcast ds_read_b128 per
// target per wave amortized over 64 lanes x QP=16 queries -> LDS pipe ~5 µs
// << VALU ~12 µs: VALU-bound at 3.5 ops/pair (3 fma + v_min3 per 2 targets).
__global__ void __launch_bounds__(BLOCK, 4) chamfer_kernel(
    const float* __restrict__ pred,
    const float* __restrict__ targ,
    float* __restrict__ mins)
{
    // union region: first ME+2 float4 = target stage; reused as smin[QP][WAVES][64]
    __shared__ float4 shbuf[QP * WAVES * 16];   // 32 KB
    float4* ts = shbuf;
    float*  smin = (float*)shbuf;

    const int tid  = threadIdx.x;
    const int lane = tid & 63;
    const int wave = tid >> 6;

    const int id     = blockIdx.x;
    const int eighth = id & (NE - 1);
    const int tile   = (id >> 3) & (QTILES - 1);
    const int b      = (id >> 5) & (Bb - 1);
    const int dir    = id >> 8;

    const float* Q = dir ? targ : pred;
    const float* T = dir ? pred : targ;

    // ---- stage this M-eighth as float4(x,y,z,|t|^2); +2 inf pad ----
    if (tid < ME) {
        const float* g = T + ((size_t)b * Mm + eighth * ME + tid) * 3;
        float x = g[0], y = g[1], z = g[2];
        ts[tid] = make_float4(x, y, z, fmaf(x, x, fmaf(y, y, z * z)));
    }
    if (tid < 2) ts[ME + tid] = make_float4(0.f, 0.f, 0.f, __builtin_inff());

    // ---- this thread's QP query points ----
    float npx[QP], npy[QP], npz[QP], pp[QP], mn[QP];
    #pragma unroll
    for (int q = 0; q < QP; ++q) {
        const int n = tile * (64 * QP) + q * 64 + lane;
        const float* g = Q + ((size_t)b * Nn + n) * 3;
        float x = g[0], y = g[1], z = g[2];
        npx[q] = -2.0f * x;  npy[q] = -2.0f * y;  npz[q] = -2.0f * z;
        pp[q]  = fmaf(x, x, fmaf(y, y, z * z));
        mn[q]  = __builtin_inff();
    }

    __syncthreads();

    // ---- main loop: 2-deep register prefetch over this wave's slice ----
    const float4* tw = ts + wave * SLICE;
    float4 t0 = tw[0], t1 = tw[1];
    for (int m = 0; m < SLICE; m += 2) {
        float4 u0 = tw[m + 2], u1 = tw[m + 3];
        #pragma unroll
        for (int q = 0; q < QP; ++q) {
            float dA = fmaf(npx[q], t0.x, fmaf(npy[q], t0.y, fmaf(npz[q], t0.z, t0.w)));
            float dB = fmaf(npx[q], t1.x, fmaf(npy[q], t1.y, fmaf(npz[q], t1.z, t1.w)));
            mn[q] = fminf(fminf(mn[q], dA), dB);          // -> v_min3_f32
        }
        t0 = u0; t1 = u1;
    }

    __syncthreads();                    // done reading ts -> reuse as smin
    #pragma unroll
    for (int q = 0; q < QP; ++q)
        smin[(q * WAVES + wave) * 64 + lane] = mn[q];
    __syncthreads();

    // ---- cross-wave min: wave w reduces q in {2w, 2w+1}; write partial ----
    #pragma unroll
    for (int k = 0; k < QP / WAVES; ++k) {
        const int q = wave * (QP / WAVES) + k;   // this thread holds pp[q]
        float v = __builtin_inff();
        #pragma unroll
        for (int w = 0; w < WAVES; ++w)
            v = fminf(v, smin[(q * WAVES + w) * 64 + lane]);
        const int n = tile * (64 * QP) + q * 64 + lane;
        const size_t qg = ((size_t)dir * Bb + b) * Nn + n;
        mins[qg * NE + eighth] = pp[q] + v;
    }
}

// 128 blocks x 256 thr: min over NE eighths, per-block partial sums (no atomics)
__global__ void __launch_bounds__(256) reduce_kernel(
    const float* __restrict__ mins, const float* __restrict__ unc,
    float* __restrict__ partials)
{
    const int q = blockIdx.x * 256 + threadIdx.x;    // [0, 32768)
    const float4* m4 = (const float4*)mins;          // 2 float4 per query

    float4 a0 = m4[2 * q],               a1 = m4[2 * q + 1];
    float4 b0 = m4[2 * (q + 32768)],     b1 = m4[2 * (q + 32768) + 1];
    float vA = fminf(fminf(fminf(a0.x, a0.y), fminf(a0.z, a0.w)),
                     fminf(fminf(a1.x, a1.y), fminf(a1.z, a1.w)));
    float vB = fminf(fminf(fminf(b0.x, b0.y), fminf(b0.z, b0.w)),
                     fminf(fminf(b1.x, b1.y), fminf(b1.z, b1.w)));
    float sA = vA, sE = sqrtf(fmaxf(vA, 0.f)), sB = vB, sU = unc[q];

    #pragma unroll
    for (int off = 32; off > 0; off >>= 1) {
        sA += __shfl_down(sA, off);  sE += __shfl_down(sE, off);
        sB += __shfl_down(sB, off);  sU += __shfl_down(sU, off);
    }
    __shared__ float sw[4][4];
    const int lane = threadIdx.x & 63, wave = threadIdx.x >> 6;
    if (lane == 0) { sw[wave][0] = sA; sw[wave][1] = sE;
                     sw[wave][2] = sB; sw[wave][3] = sU; }
    __syncthreads();
    if (threadIdx.x < 4) {
        partials[blockIdx.x * 4 + threadIdx.x] =
            sw[0][threadIdx.x] + sw[1][threadIdx.x] +
            sw[2][threadIdx.x] + sw[3][threadIdx.x];
    }
}

__global__ void __launch_bounds__(64) finalize_kernel(
    const float* __restrict__ partials, float* __restrict__ out)
{
    const float4* p4 = (const float4*)partials;      // 128 rows of 4
    float4 s0 = p4[threadIdx.x], s1 = p4[threadIdx.x + 64];
    float sA = s0.x + s1.x, sE = s0.y + s1.y, sB = s0.z + s1.z, sU = s0.w + s1.w;
    #pragma unroll
    for (int off = 32; off > 0; off >>= 1) {
        sA += __shfl_down(sA, off);  sE += __shfl_down(sE, off);
        sB += __shfl_down(sB, off);  sU += __shfl_down(sU, off);
    }
    if (threadIdx.x == 0) {
        const float invBN = 1.0f / (float)(Bb * Nn);
        const float invBM = 1.0f / (float)(Bb * Mm);
        out[0] = (sA * invBN + sB * invBM) + 0.5f * (sE * invBN)
               + 0.01f * (sU * invBN);
    }
}

extern "C" void kernel_launch(void* const* d_in, const int* in_sizes, int n_in,
                              void* d_out, int out_size, void* d_ws, size_t ws_size,
                              hipStream_t stream) {
    const float* pred = (const float*)d_in[0];   // [8,4096,3]
    const float* targ = (const float*)d_in[1];   // [8,4096,3]
    const float* unc  = (const float*)d_in[2];   // [8,4096]
    float* out      = (float*)d_out;
    float* mins     = (float*)d_ws;              // NQ x NE floats = 2 MB
    float* partials = (float*)d_ws + (size_t)NQ * NE;  // 128 x 4 floats

    chamfer_kernel<<<512, BLOCK, 0, stream>>>(pred, targ, mins);
    reduce_kernel<<<128, 256, 0, stream>>>(mins, unc, partials);
    finalize_kernel<<<1, 64, 0, stream>>>(partials, out);
}

// Round 6
// 32.983 us; speedup vs baseline: 1.6499x; 1.0257x over previous
//
#include <hip/hip_runtime.h>
#include <math.h>

typedef float v2f __attribute__((ext_vector_type(2)));

#define Bb 8
#define Nn 4096
#define Mm 4096
#define QP 16                   // query points per thread (registers)
#define WAVES 8                 // waves per block
#define BLOCK (WAVES * 64)      // 512 threads
#define NE 8                    // M split into eighths
#define ME (Mm / NE)            // 512 targets per eighth
#define PAIRS (ME / 2)          // 256 target pairs (pair-transposed in LDS)
#define SLICEP (PAIRS / WAVES)  // 32 pairs per wave
#define QTILES (Nn / (64 * QP)) // 4 query tiles per (dir,b)
#define NQ (2 * Bb * Nn)        // 65536 query slots (both dirs)

// d_ws layout:
//   mins[NQ][NE]     : per-query per-eighth partial (pp + min_eighth), 2 MB
//   partials[128][4] : per-reduce-block {chamferA, emd, chamferB, unc} sums
// Every slot rewritten every call (no memset, no atomics, deterministic).

// grid = 2 dirs x 8 batches x 4 qtiles x 8 eighths = 512 blocks of 512 thr
// (2 blocks/CU, 4 waves/SIMD). Inner math: v_pk_fma_f32 (VOP3P packed f32):
// 3 pk_fma + 1 v_min3 per (query, target-PAIR) = 2 VALU instr per pair,
// query scalar broadcast into both packed lanes via op_sel word-select.
// LDS: targets pair-transposed {x0,x1,y0,y1},{z0,z1,w0,w1} -> 2 ds_read_b128
// per pair per wave, amortized over 64 lanes x QP=16 queries.
__global__ void __launch_bounds__(BLOCK, 4) chamfer_kernel(
    const float* __restrict__ pred,
    const float* __restrict__ targ,
    float* __restrict__ mins)
{
    // union region: target stage (514 float4) reused as smin[QP][WAVES][64]
    __shared__ float4 shbuf[QP * WAVES * 16];   // 32 KB
    float4* ts   = shbuf;
    float*  smin = (float*)shbuf;

    const int tid  = threadIdx.x;
    const int lane = tid & 63;
    const int wave = tid >> 6;

    const int id     = blockIdx.x;
    const int eighth = id & (NE - 1);
    const int tile   = (id >> 3) & (QTILES - 1);
    const int b      = (id >> 5) & (Bb - 1);
    const int dir    = id >> 8;

    const float* Q = dir ? targ : pred;
    const float* T = dir ? pred : targ;

    // ---- stage this M-eighth, pair-transposed, with |t|^2 ----
    if (tid < PAIRS) {
        const float2* g2 = (const float2*)(T + ((size_t)b * Mm + eighth * ME + 2 * tid) * 3);
        float2 f01 = g2[0], f23 = g2[1], f45 = g2[2];
        float x0 = f01.x, y0 = f01.y, z0 = f23.x;
        float x1 = f23.y, y1 = f45.x, z1 = f45.y;
        float w0 = fmaf(x0, x0, fmaf(y0, y0, z0 * z0));
        float w1 = fmaf(x1, x1, fmaf(y1, y1, z1 * z1));
        ts[2 * tid]     = make_float4(x0, x1, y0, y1);
        ts[2 * tid + 1] = make_float4(z0, z1, w0, w1);
    }
    if (tid == 0) {  // pad pair for the last wave's 1-deep prefetch
        ts[2 * PAIRS]     = make_float4(0.f, 0.f, 0.f, 0.f);
        ts[2 * PAIRS + 1] = make_float4(0.f, 0.f, __builtin_inff(), __builtin_inff());
    }

    // ---- this thread's QP query points: {-2x,-2y}, {-2z, |p|^2} ----
    v2f qxy[QP], qzp[QP];
    float mn[QP];
    #pragma unroll
    for (int q = 0; q < QP; ++q) {
        const int n = tile * (64 * QP) + q * 64 + lane;
        const float* g = Q + ((size_t)b * Nn + n) * 3;
        float x = g[0], y = g[1], z = g[2];
        qxy[q][0] = -2.0f * x;  qxy[q][1] = -2.0f * y;
        qzp[q][0] = -2.0f * z;  qzp[q][1] = fmaf(x, x, fmaf(y, y, z * z));
        mn[q] = __builtin_inff();
    }

    __syncthreads();

    // ---- main loop: 1 pair (2 targets) per iter, 1-deep register prefetch ----
    const float4* tw = ts + wave * (SLICEP * 2);
    float4 c0 = tw[0], c1 = tw[1];
    for (int m = 0; m < SLICEP; ++m) {
        float4 n0 = tw[2 * m + 2], n1 = tw[2 * m + 3];
        v2f xx, yy, zz, ww;
        xx[0] = c0.x; xx[1] = c0.y;  yy[0] = c0.z; yy[1] = c0.w;
        zz[0] = c1.x; zz[1] = c1.y;  ww[0] = c1.z; ww[1] = c1.w;
        #pragma unroll
        for (int q = 0; q < QP; ++q) {
            v2f d0, d1, d2v;
            // d = (-2z)*zz + ww          (broadcast qzp.lo to both lanes)
            asm("v_pk_fma_f32 %0, %1, %2, %3 op_sel_hi:[0,1,1]"
                : "=v"(d0) : "v"(qzp[q]), "v"(zz), "v"(ww));
            // d = (-2y)*yy + d           (broadcast qxy.hi to both lanes)
            asm("v_pk_fma_f32 %0, %1, %2, %3 op_sel:[1,0,0] op_sel_hi:[1,1,1]"
                : "=v"(d1) : "v"(qxy[q]), "v"(yy), "v"(d0));
            // d = (-2x)*xx + d           (broadcast qxy.lo to both lanes)
            asm("v_pk_fma_f32 %0, %1, %2, %3 op_sel_hi:[0,1,1]"
                : "=v"(d2v) : "v"(qxy[q]), "v"(xx), "v"(d1));
            mn[q] = fminf(fminf(mn[q], d2v[0]), d2v[1]);   // -> v_min3_f32
        }
        c0 = n0; c1 = n1;
    }

    // ---- fold |p|^2 in with STATIC q index (avoids scratch demotion) ----
    __syncthreads();                    // done reading ts -> reuse as smin
    #pragma unroll
    for (int q = 0; q < QP; ++q)
        smin[(q * WAVES + wave) * 64 + lane] = mn[q] + qzp[q][1];
    __syncthreads();

    // ---- cross-wave min: wave w reduces q in {2w, 2w+1}; write partial ----
    #pragma unroll
    for (int k = 0; k < QP / WAVES; ++k) {
        const int q = wave * (QP / WAVES) + k;
        float v = smin[(q * WAVES + 0) * 64 + lane];
        #pragma unroll
        for (int w = 1; w < WAVES; ++w)
            v = fminf(v, smin[(q * WAVES + w) * 64 + lane]);
        const int n = tile * (64 * QP) + q * 64 + lane;
        const size_t qg = ((size_t)dir * Bb + b) * Nn + n;
        mins[qg * NE + eighth] = v;
    }
}

// 128 blocks x 256 thr: min over NE eighths, per-block partial sums (no atomics)
__global__ void __launch_bounds__(256) reduce_kernel(
    const float* __restrict__ mins, const float* __restrict__ unc,
    float* __restrict__ partials)
{
    const int q = blockIdx.x * 256 + threadIdx.x;    // [0, 32768)
    const float4* m4 = (const float4*)mins;          // 2 float4 per query

    float4 a0 = m4[2 * q],           a1 = m4[2 * q + 1];
    float4 b0 = m4[2 * (q + 32768)], b1 = m4[2 * (q + 32768) + 1];
    float vA = fminf(fminf(fminf(a0.x, a0.y), fminf(a0.z, a0.w)),
                     fminf(fminf(a1.x, a1.y), fminf(a1.z, a1.w)));
    float vB = fminf(fminf(fminf(b0.x, b0.y), fminf(b0.z, b0.w)),
                     fminf(fminf(b1.x, b1.y), fminf(b1.z, b1.w)));
    float sA = vA, sE = sqrtf(fmaxf(vA, 0.f)), sB = vB, sU = unc[q];

    #pragma unroll
    for (int off = 32; off > 0; off >>= 1) {
        sA += __shfl_down(sA, off);  sE += __shfl_down(sE, off);
        sB += __shfl_down(sB, off);  sU += __shfl_down(sU, off);
    }
    __shared__ float sw[4][4];
    const int lane = threadIdx.x & 63, wave = threadIdx.x >> 6;
    if (lane == 0) { sw[wave][0] = sA; sw[wave][1] = sE;
                     sw[wave][2] = sB; sw[wave][3] = sU; }
    __syncthreads();
    if (threadIdx.x < 4) {
        partials[blockIdx.x * 4 + threadIdx.x] =
            sw[0][threadIdx.x] + sw[1][threadIdx.x] +
            sw[2][threadIdx.x] + sw[3][threadIdx.x];
    }
}

__global__ void __launch_bounds__(64) finalize_kernel(
    const float* __restrict__ partials, float* __restrict__ out)
{
    const float4* p4 = (const float4*)partials;      // 128 rows of 4
    float4 s0 = p4[threadIdx.x], s1 = p4[threadIdx.x + 64];
    float sA = s0.x + s1.x, sE = s0.y + s1.y, sB = s0.z + s1.z, sU = s0.w + s1.w;
    #pragma unroll
    for (int off = 32; off > 0; off >>= 1) {
        sA += __shfl_down(sA, off);  sE += __shfl_down(sE, off);
        sB += __shfl_down(sB, off);  sU += __shfl_down(sU, off);
    }
    if (threadIdx.x == 0) {
        const float invBN = 1.0f / (float)(Bb * Nn);
        const float invBM = 1.0f / (float)(Bb * Mm);
        out[0] = (sA * invBN + sB * invBM) + 0.5f * (sE * invBN)
               + 0.01f * (sU * invBN);
    }
}

extern "C" void kernel_launch(void* const* d_in, const int* in_sizes, int n_in,
                              void* d_out, int out_size, void* d_ws, size_t ws_size,
                              hipStream_t stream) {
    const float* pred = (const float*)d_in[0];   // [8,4096,3]
    const float* targ = (const float*)d_in[1];   // [8,4096,3]
    const float* unc  = (const float*)d_in[2];   // [8,4096]
    float* out      = (float*)d_out;
    float* mins     = (float*)d_ws;                    // NQ x NE floats = 2 MB
    float* partials = (float*)d_ws + (size_t)NQ * NE;  // 128 x 4 floats

    chamfer_kernel<<<512, BLOCK, 0, stream>>>(pred, targ, mins);
    reduce_kernel<<<128, 256, 0, stream>>>(mins, unc, partials);
    finalize_kernel<<<1, 64, 0, stream>>>(partials, out);
}